// Round 2
// baseline (109.895 us; speedup 1.0000x reference)
//
#include <hip/hip_runtime.h>

// Sliding-window causal attention, B=2 H=16 N=2048 D=64 W=512, fp32 in/out.
// R9 (= R8 resubmit with canonical addrspace casts in gload16):
//   swa_prep: one-shot fp32->bf16 conversion of K and V^T into per-tile 8KB
//     "LDS images" in workspace, pre-chunk-XOR-swizzled and pre-transposed so
//     the main kernel can stage with linear global_load_lds (wave-uniform dest,
//     no VGPR round-trip, no conversion VALU, no ds_write).
//   swa_fused: BM=128, 512 thr, 8 waves x 1 strip. S^T operand-swap flash
//     attention (P stays in-lane between QK and PV MFMAs, denom reduced once
//     in the epilogue). Per-tile double buffer, 1 barrier/iter; staging is now
//     2 x global_load_lds dwordx4 per thread per tile, issued for t+1 before
//     tile-t compute so HBM latency hides under MFMA+softmax.

#define SEQ 2048
#define HD  64

typedef short short8 __attribute__((ext_vector_type(8)));
typedef float f32x4  __attribute__((ext_vector_type(4)));
typedef int   i32x4  __attribute__((ext_vector_type(4)));

static __device__ inline unsigned short f2bf(float f){
  union{float f; unsigned u;} un; un.f=f;
  return (unsigned short)((un.u + 0x7FFFu + ((un.u>>16)&1u))>>16);
}
static __device__ inline int swz(int row){ return (row&3)|(((row>>3)&1)<<2); }

// global->LDS direct load, 16B per lane. LDS dest is wave-uniform base +
// lane*16 (hardware); global src is per-lane. Canonical addrspace casts:
// generic->AS(1) for the global source, generic->AS(3) for the LDS dest
// (compiler emits the proper addrspacecast; no aperture assumptions).
static __device__ __forceinline__ void gload16(const void* g, void* l){
  __builtin_amdgcn_global_load_lds(
      (const __attribute__((address_space(1))) void*)g,
      (__attribute__((address_space(3))) void*)l,
      16, 0, 0);
}

// ---------------------------------------------------------------------------
// Prep: for each (bh, tile t) write the exact 8KB bf16 LDS image of K and of
// V^T (chunk-XOR-swizzled) that swa_fused expects. One block per (bh,t).
// ---------------------------------------------------------------------------
__global__ __launch_bounds__(512) void swa_prep(
    const float* __restrict__ k, const float* __restrict__ v,
    unsigned short* __restrict__ kp, unsigned short* __restrict__ vp)
{
  const int tid=threadIdx.x, bid=blockIdx.x;      // bid = bh*32 + t
  const long fbase=(long)bid*4096;                // float offset of this tile
  const long ib  =(long)bid*4096;                 // short offset of this image

  // K image: row-major [key(64)][d(64)] bf16, chunks XOR-swizzled per row.
  {
    const int kr=tid>>3, klc=tid&7;
    const float* kt=k+fbase+kr*64+klc*8;
    float4 f0=*(const float4*)kt;
    float4 f1=*(const float4*)(kt+4);
    unsigned short h[8];
    h[0]=f2bf(f0.x); h[1]=f2bf(f0.y); h[2]=f2bf(f0.z); h[3]=f2bf(f0.w);
    h[4]=f2bf(f1.x); h[5]=f2bf(f1.y); h[6]=f2bf(f1.z); h[7]=f2bf(f1.w);
    *(uint4*)&kp[ib + kr*64 + ((klc^swz(kr))*8)] = *(uint4*)h;
  }
  // V image: transposed [d(64)][key(64)] bf16, chunks XOR-swizzled per d-row.
  {
    const int vw=tid>>6, vd=tid&63;
    const float* vt=v+fbase;
    unsigned short h[8];
    #pragma unroll
    for(int j=0;j<8;++j) h[j]=f2bf(vt[(vw*8+j)*64+vd]);
    *(uint4*)&vp[ib + vd*64 + ((vw^swz(vd))*8)] = *(uint4*)h;
  }
}

// ---------------------------------------------------------------------------
// Fused flash attention over pre-converted tile images.
// ---------------------------------------------------------------------------
__global__ __launch_bounds__(512) void swa_fused(
    const float* __restrict__ q, const unsigned short* __restrict__ kp,
    const unsigned short* __restrict__ vp, float* __restrict__ out)
{
  __shared__ unsigned short Ks[2][4096];    // [key(64)][d(64)] bf16, swizzled
  __shared__ unsigned short Vsh[2][4096];   // [d(64)][key(64)] bf16, swizzled

  const int tid=threadIdx.x, bid=blockIdx.x;
  const int mt=bid&15, bh=bid>>4, m0=mt*128;
  const long base=(long)bh*SEQ*HD;
  const int wv=tid>>6, lane=tid&63, quad=lane>>4, l16=lane&15;
  const int qrow=m0+wv*16+l16;
  const int h=wv>>2;                        // block half (rows 0-63 / 64-127)

  // ---- Q B-fragment, softmax scale folded here (Q loaded once per block) ----
  short8 qa[2];
  {
    const float C=0.18033688011112042f;     // 0.125 * log2(e)
    const float* qp=q+base+(long)qrow*HD+quad*8;
    #pragma unroll
    for(int kk=0;kk<2;++kk){
      float4 f0=*(const float4*)(qp+kk*32);
      float4 f1=*(const float4*)(qp+kk*32+4);
      short8 a;
      a[0]=(short)f2bf(f0.x*C); a[1]=(short)f2bf(f0.y*C);
      a[2]=(short)f2bf(f0.z*C); a[3]=(short)f2bf(f0.w*C);
      a[4]=(short)f2bf(f1.x*C); a[5]=(short)f2bf(f1.y*C);
      a[6]=(short)f2bf(f1.z*C); a[7]=(short)f2bf(f1.w*C);
      qa[kk]=a;
    }
  }

  // ---- per-lane constant LDS fragment offsets (R6/R7-verified in-lane-P map) ----
  const int rbase=8*(l16>>2)+(l16&3);
  const int swk=(l16&3)|(((l16>>2)&1)<<2);  // = swz(ka row), nt-independent
  const int swv=(l16&3)|(((l16>>3)&1)<<2);  // = swz(vb row), dt-independent
  int kaoff[2][4], vboff[2][4];
  #pragma unroll
  for(int kk=0;kk<2;++kk){
    #pragma unroll
    for(int nt=0;nt<4;++nt)
      kaoff[kk][nt]=(rbase+(nt&1)*4+(nt>>1)*32)*64+(((quad+4*kk)^swk)*8);
    #pragma unroll
    for(int dt=0;dt<4;++dt)
      vboff[kk][dt]=(dt*16+l16)*64+(((quad+4*kk)^swv)*8);
  }

  // ---- staging: per-lane image pointer + wave-uniform LDS dest ----
  const unsigned short* kimg = kp + (long)bh*32*4096 + tid*8;  // lane's 16B
  const unsigned short* vimg = vp + (long)bh*32*4096 + tid*8;
  unsigned short* kdst = &Ks[0][wv*512];    // + buf*4096 shorts for buffer 1
  unsigned short* vdst = &Vsh[0][wv*512];

  f32x4 oacc[4];
  #pragma unroll
  for(int dt=0;dt<4;++dt) oacc[dt]=(f32x4){0.f,0.f,0.f,0.f};
  float lrun=0.f;

  const int Tb =2*mt+1;
  const int Tlo=(2*mt>8)?(2*mt-8):0;
  const int myTb=2*mt+h;
  const bool clip=(myTb>=8);
  const int myTlo=clip?(myTb-8):0;

  // ---- stage tile Tlo -> buf0 ----
  gload16(kimg+(long)Tlo*4096, kdst);
  gload16(vimg+(long)Tlo*4096, vdst);
  __syncthreads();

  for(int t=Tlo;t<=Tb;++t){
    const int buf=(t-Tlo)&1;

    // ---- issue direct-to-LDS prefetch for tile t+1 into the other buffer ----
    // (previous round's barrier guarantees no wave still reads buf^1)
    if(t<Tb){
      gload16(kimg+(long)(t+1)*4096, kdst+(buf^1)*4096);
      gload16(vimg+(long)(t+1)*4096, vdst+(buf^1)*4096);
    }

    if(t>=myTlo && t<=myTb){                // wave-uniform tile skip
      // ---- S^T = K Q^T ----
      f32x4 sacc[4];
      #pragma unroll
      for(int nt=0;nt<4;++nt) sacc[nt]=(f32x4){0.f,0.f,0.f,0.f};
      #pragma unroll
      for(int kk=0;kk<2;++kk)
        #pragma unroll
        for(int nt=0;nt<4;++nt){
          short8 ka=*(const short8*)&Ks[buf][kaoff[kk][nt]];
          sacc[nt]=__builtin_amdgcn_mfma_f32_16x16x32_bf16(ka,qa[kk],sacc[nt],0,0,0);
        }

      // ---- p = exp2(s); mask only on boundary tiles; trunc-pack (in-lane) ----
      unsigned pp[8];
      float ls=0.f;
      const bool msk=(t==myTb)||(clip&&t==myTlo);
      #pragma unroll
      for(int nt=0;nt<4;++nt){
        float e0=__builtin_amdgcn_exp2f(sacc[nt][0]);
        float e1=__builtin_amdgcn_exp2f(sacc[nt][1]);
        float e2=__builtin_amdgcn_exp2f(sacc[nt][2]);
        float e3=__builtin_amdgcn_exp2f(sacc[nt][3]);
        if(msk){
          const int kb0=t*64+8*quad+(nt&1)*4+(nt>>1)*32;
          e0=((kb0+0<=qrow)&&(kb0+0+511>=qrow))?e0:0.f;
          e1=((kb0+1<=qrow)&&(kb0+1+511>=qrow))?e1:0.f;
          e2=((kb0+2<=qrow)&&(kb0+2+511>=qrow))?e2:0.f;
          e3=((kb0+3<=qrow)&&(kb0+3+511>=qrow))?e3:0.f;
        }
        ls+=e0+e1+e2+e3;
        pp[nt*2+0]=(__float_as_uint(e1)&0xFFFF0000u)|(__float_as_uint(e0)>>16);
        pp[nt*2+1]=(__float_as_uint(e3)&0xFFFF0000u)|(__float_as_uint(e2)>>16);
      }
      lrun+=ls;
      i32x4 i0={(int)pp[0],(int)pp[1],(int)pp[2],(int)pp[3]};
      i32x4 i1={(int)pp[4],(int)pp[5],(int)pp[6],(int)pp[7]};
      short8 pa0=*(short8*)&i0;
      short8 pa1=*(short8*)&i1;

      // ---- O += P V ----
      #pragma unroll
      for(int dt=0;dt<4;++dt){
        short8 vb0=*(const short8*)&Vsh[buf][vboff[0][dt]];
        short8 vb1=*(const short8*)&Vsh[buf][vboff[1][dt]];
        oacc[dt]=__builtin_amdgcn_mfma_f32_16x16x32_bf16(pa0,vb0,oacc[dt],0,0,0);
        oacc[dt]=__builtin_amdgcn_mfma_f32_16x16x32_bf16(pa1,vb1,oacc[dt],0,0,0);
      }
    }

    __syncthreads();   // drains vmcnt -> prefetched tile resident in buf^1
  }

  // ---- epilogue: l = sum over the 4 quads (disjoint key subsets per quad) ----
  lrun+=__shfl_xor(lrun,16);
  lrun+=__shfl_xor(lrun,32);
  float linv=1.0f/lrun;                     // diagonal always contributes > 0
  #pragma unroll
  for(int r=0;r<4;++r){
    float lr=__shfl(linv,quad*4+r);         // lane (quad*4+r) holds that row's l
    const int orow=m0+wv*16+quad*4+r;
    #pragma unroll
    for(int dt=0;dt<4;++dt)
      out[base+(long)orow*HD+dt*16+l16]=oacc[dt][r]*lr;
  }
}

extern "C" void kernel_launch(void* const* d_in, const int* in_sizes, int n_in,
                              void* d_out, int out_size, void* d_ws, size_t ws_size,
                              hipStream_t stream) {
  (void)in_sizes; (void)n_in; (void)out_size; (void)ws_size;
  const float* q=(const float*)d_in[0];
  const float* k=(const float*)d_in[1];
  const float* v=(const float*)d_in[2];
  float* o=(float*)d_out;
  // Workspace layout (ws is 256MiB, we need 16MiB):
  //   [0, 8MiB)   K tile images: 32 bh x 32 tiles x 4096 bf16
  //   [8, 16MiB)  V^T tile images: same shape
  unsigned short* kp=(unsigned short*)d_ws;
  unsigned short* vp=kp + (long)32*32*4096;
  hipLaunchKernelGGL(swa_prep,  dim3(1024), dim3(512), 0, stream, k, v, kp, vp);
  hipLaunchKernelGGL(swa_fused, dim3(512),  dim3(512), 0, stream, q, kp, vp, o);
}

// Round 3
// 109.264 us; speedup vs baseline: 1.0058x; 1.0058x over previous
//
#include <hip/hip_runtime.h>

// Sliding-window causal attention, B=2 H=16 N=2048 D=64 W=512, fp32 in/out.
// R10: revert R9's prep-kernel split (net-negative: the 50MB conversion pass
//   + extra launch exceeded the staging VALU it removed; measured 109.9 vs
//   108.4). Back to the single fused kernel (R7 structure), plus KVBLK=128:
//   two 64-key sub-tiles staged + computed per barrier -> half the barriers
//   and convert/ds_write drain tails, 32 MFMA per phase, half the loop
//   overhead. LDS 64KB (2 blocks/CU), __launch_bounds__(512,4) pins VGPR<=128
//   so 16 waves/CU survive the doubled staging registers.
//   Everything else is the R7-verified machinery: S^T operand-swap flash
//   attention (P stays in-lane between QK and PV MFMAs, denom reduced once in
//   the epilogue), fp32->bf16 staged inline into chunk-XOR-swizzled LDS,
//   per-pair double buffer, global prefetch issued before compute.

#define SEQ 2048
#define HD  64

typedef short short8 __attribute__((ext_vector_type(8)));
typedef float f32x4  __attribute__((ext_vector_type(4)));
typedef int   i32x4  __attribute__((ext_vector_type(4)));

static __device__ inline unsigned short f2bf(float f){
  union{float f; unsigned u;} un; un.f=f;
  return (unsigned short)((un.u + 0x7FFFu + ((un.u>>16)&1u))>>16);
}
static __device__ inline int swz(int row){ return (row&3)|(((row>>3)&1)<<2); }

__global__ __launch_bounds__(512,4) void swa_fused(
    const float* __restrict__ q, const float* __restrict__ k,
    const float* __restrict__ v, float* __restrict__ out)
{
  __shared__ unsigned short Ks[2][2][4096];   // [buf][sub][key(64)][d(64)] bf16, swizzled
  __shared__ unsigned short Vsh[2][2][4096];  // [buf][sub][d(64)][key(64)] bf16, swizzled

  const int tid=threadIdx.x, bid=blockIdx.x;
  const int mt=bid&15, bh=bid>>4, m0=mt*128;
  const long base=(long)bh*SEQ*HD;
  const int wv=tid>>6, lane=tid&63, quad=lane>>4, l16=lane&15;
  const int qrow=m0+wv*16+l16;
  const int h=wv>>2;                        // block half (rows 0-63 / 64-127)

  // ---- Q B-fragment, softmax scale folded here (Q loaded once per block) ----
  short8 qa[2];
  {
    const float C=0.18033688011112042f;     // 0.125 * log2(e)
    const float* qp=q+base+(long)qrow*HD+quad*8;
    #pragma unroll
    for(int kk=0;kk<2;++kk){
      float4 f0=*(const float4*)(qp+kk*32);
      float4 f1=*(const float4*)(qp+kk*32+4);
      short8 a;
      a[0]=(short)f2bf(f0.x*C); a[1]=(short)f2bf(f0.y*C);
      a[2]=(short)f2bf(f0.z*C); a[3]=(short)f2bf(f0.w*C);
      a[4]=(short)f2bf(f1.x*C); a[5]=(short)f2bf(f1.y*C);
      a[6]=(short)f2bf(f1.z*C); a[7]=(short)f2bf(f1.w*C);
      qa[kk]=a;
    }
  }

  // ---- per-lane constant LDS fragment offsets (R6/R7-verified in-lane-P map) ----
  const int rbase=8*(l16>>2)+(l16&3);
  const int swk=(l16&3)|(((l16>>2)&1)<<2);  // = swz(ka row), nt-independent
  const int swv=(l16&3)|(((l16>>3)&1)<<2);  // = swz(vb row), dt-independent
  int kaoff[2][4], vboff[2][4];
  #pragma unroll
  for(int kk=0;kk<2;++kk){
    #pragma unroll
    for(int nt=0;nt<4;++nt)
      kaoff[kk][nt]=(rbase+(nt&1)*4+(nt>>1)*32)*64+(((quad+4*kk)^swk)*8);
    #pragma unroll
    for(int dt=0;dt<4;++dt)
      vboff[kk][dt]=(dt*16+l16)*64+(((quad+4*kk)^swv)*8);
  }

  // ---- staging geometry (512 thr cover one 64x64 tile each for K and V) ----
  const int kr=tid>>3, klc=tid&7;                 // K: row, logical chunk
  const int kwaddr=kr*64+((klc^swz(kr))*8);       // swizzled write addr (shorts)
  const int vw=tid>>6, vd=tid&63;                 // V: key-chunk, d-column
  const int vwaddr=vd*64+((vw^swz(vd))*8);
  const float* kg=k+base;
  const float* vg=v+base;

  f32x4 oacc[4];
  #pragma unroll
  for(int dt=0;dt<4;++dt) oacc[dt]=(f32x4){0.f,0.f,0.f,0.f};
  float lrun=0.f;

  const int Tb =2*mt+1;
  const int Tlo=(2*mt>8)?(2*mt-8):0;              // always even
  const int myTb=2*mt+h;
  const bool clip=(myTb>=8);
  const int myTlo=clip?(myTb-8):0;
  const int nR=(Tb-Tlo+2)>>1;                     // tile count is always even

  // ---- prologue: stage pair (Tlo, Tlo+1) -> buf0 ----
  #pragma unroll
  for(int s=0;s<2;++s){
    const float* kt=kg+(long)(Tlo+s)*4096;
    const float* vt=vg+(long)(Tlo+s)*4096;
    float4 f0=*(const float4*)(kt+kr*64+klc*8);
    float4 f1=*(const float4*)(kt+kr*64+klc*8+4);
    unsigned short hk[8];
    hk[0]=f2bf(f0.x); hk[1]=f2bf(f0.y); hk[2]=f2bf(f0.z); hk[3]=f2bf(f0.w);
    hk[4]=f2bf(f1.x); hk[5]=f2bf(f1.y); hk[6]=f2bf(f1.z); hk[7]=f2bf(f1.w);
    *(uint4*)&Ks[0][s][kwaddr]=*(uint4*)hk;
    unsigned short hv[8];
    #pragma unroll
    for(int j=0;j<8;++j) hv[j]=f2bf(vt[(vw*8+j)*64+vd]);
    *(uint4*)&Vsh[0][s][vwaddr]=*(uint4*)hv;
  }
  __syncthreads();

  for(int r=0;r<nR;++r){
    const int buf=r&1;
    const bool pf=(r+1<nR);

    // ---- issue global prefetch for pair r+1 (latency hides under compute) ----
    float4 kf0[2],kf1[2]; float vf[2][8];
    if(pf){
      #pragma unroll
      for(int s=0;s<2;++s){
        const int tn=Tlo+2*r+2+s;
        const float* kt=kg+(long)tn*4096;
        const float* vt=vg+(long)tn*4096;
        kf0[s]=*(const float4*)(kt+kr*64+klc*8);
        kf1[s]=*(const float4*)(kt+kr*64+klc*8+4);
        #pragma unroll
        for(int j=0;j<8;++j) vf[s][j]=vt[(vw*8+j)*64+vd];
      }
    }

    // ---- compute the two resident sub-tiles (32 MFMA per barrier) ----
    #pragma unroll
    for(int s=0;s<2;++s){
      const int t=Tlo+2*r+s;
      if(t>=myTlo && t<=myTb){              // wave-uniform tile skip
        // ---- S^T = K Q^T ----
        f32x4 sacc[4];
        #pragma unroll
        for(int nt=0;nt<4;++nt) sacc[nt]=(f32x4){0.f,0.f,0.f,0.f};
        #pragma unroll
        for(int kk=0;kk<2;++kk)
          #pragma unroll
          for(int nt=0;nt<4;++nt){
            short8 ka=*(const short8*)&Ks[buf][s][kaoff[kk][nt]];
            sacc[nt]=__builtin_amdgcn_mfma_f32_16x16x32_bf16(ka,qa[kk],sacc[nt],0,0,0);
          }

        // ---- p = exp2(s); mask only on boundary tiles; trunc-pack (in-lane) ----
        unsigned pp[8];
        float ls=0.f;
        const bool msk=(t==myTb)||(clip&&t==myTlo);
        #pragma unroll
        for(int nt=0;nt<4;++nt){
          float e0=__builtin_amdgcn_exp2f(sacc[nt][0]);
          float e1=__builtin_amdgcn_exp2f(sacc[nt][1]);
          float e2=__builtin_amdgcn_exp2f(sacc[nt][2]);
          float e3=__builtin_amdgcn_exp2f(sacc[nt][3]);
          if(msk){
            const int kb0=t*64+8*quad+(nt&1)*4+(nt>>1)*32;
            e0=((kb0+0<=qrow)&&(kb0+0+511>=qrow))?e0:0.f;
            e1=((kb0+1<=qrow)&&(kb0+1+511>=qrow))?e1:0.f;
            e2=((kb0+2<=qrow)&&(kb0+2+511>=qrow))?e2:0.f;
            e3=((kb0+3<=qrow)&&(kb0+3+511>=qrow))?e3:0.f;
          }
          ls+=e0+e1+e2+e3;
          pp[nt*2+0]=(__float_as_uint(e1)&0xFFFF0000u)|(__float_as_uint(e0)>>16);
          pp[nt*2+1]=(__float_as_uint(e3)&0xFFFF0000u)|(__float_as_uint(e2)>>16);
        }
        lrun+=ls;
        i32x4 i0={(int)pp[0],(int)pp[1],(int)pp[2],(int)pp[3]};
        i32x4 i1={(int)pp[4],(int)pp[5],(int)pp[6],(int)pp[7]};
        short8 pa0=*(short8*)&i0;
        short8 pa1=*(short8*)&i1;

        // ---- O += P V ----
        #pragma unroll
        for(int dt=0;dt<4;++dt){
          short8 vb0=*(const short8*)&Vsh[buf][s][vboff[0][dt]];
          short8 vb1=*(const short8*)&Vsh[buf][s][vboff[1][dt]];
          oacc[dt]=__builtin_amdgcn_mfma_f32_16x16x32_bf16(pa0,vb0,oacc[dt],0,0,0);
          oacc[dt]=__builtin_amdgcn_mfma_f32_16x16x32_bf16(pa1,vb1,oacc[dt],0,0,0);
        }
      }
    }

    // ---- convert + write prefetched pair into the other buffer ----
    if(pf){
      #pragma unroll
      for(int s=0;s<2;++s){
        unsigned short hk[8];
        hk[0]=f2bf(kf0[s].x); hk[1]=f2bf(kf0[s].y); hk[2]=f2bf(kf0[s].z); hk[3]=f2bf(kf0[s].w);
        hk[4]=f2bf(kf1[s].x); hk[5]=f2bf(kf1[s].y); hk[6]=f2bf(kf1[s].z); hk[7]=f2bf(kf1[s].w);
        *(uint4*)&Ks[buf^1][s][kwaddr]=*(uint4*)hk;
        unsigned short hv[8];
        #pragma unroll
        for(int j=0;j<8;++j) hv[j]=f2bf(vf[s][j]);
        *(uint4*)&Vsh[buf^1][s][vwaddr]=*(uint4*)hv;
      }
    }
    __syncthreads();
  }

  // ---- epilogue: l = sum over the 4 quads (disjoint key subsets per quad) ----
  lrun+=__shfl_xor(lrun,16);
  lrun+=__shfl_xor(lrun,32);
  float linv=1.0f/lrun;                     // diagonal always contributes > 0
  #pragma unroll
  for(int r=0;r<4;++r){
    float lr=__shfl(linv,quad*4+r);         // lane (quad*4+r) holds that row's l
    const int orow=m0+wv*16+quad*4+r;
    #pragma unroll
    for(int dt=0;dt<4;++dt)
      out[base+(long)orow*HD+dt*16+l16]=oacc[dt][r]*lr;
  }
}

extern "C" void kernel_launch(void* const* d_in, const int* in_sizes, int n_in,
                              void* d_out, int out_size, void* d_ws, size_t ws_size,
                              hipStream_t stream) {
  (void)in_sizes; (void)n_in; (void)out_size; (void)d_ws; (void)ws_size;
  const float* q=(const float*)d_in[0];
  const float* k=(const float*)d_in[1];
  const float* v=(const float*)d_in[2];
  float* o=(float*)d_out;
  hipLaunchKernelGGL(swa_fused, dim3(512), dim3(512), 0, stream, q, k, v, o);
}